// Round 4
// baseline (963.446 us; speedup 1.0000x reference)
//
#include <hip/hip_runtime.h>

#define N_NODES 100000
#define N_EDGES 1600000
#define DIM 64
#define BN_EPS 1e-5f

#define BNODES 256                       // nodes per bucket
#define NBUCK ((N_NODES + BNODES - 1) / BNODES)  // 391
#define CAP 5120                         // entries per bucket (mean 4096, +16 sigma)
#define TILE 8192                        // edges per passA block

// ---- bf16 helpers (manual RNE) -------------------------------------------
static __device__ __forceinline__ unsigned short f2bf(float f) {
    unsigned u = __float_as_uint(f);
    u = (u + 0x7FFFu + ((u >> 16) & 1u)) >> 16;
    return (unsigned short)u;
}
static __device__ __forceinline__ float bf2f(unsigned short h) {
    return __uint_as_float(((unsigned)h) << 16);
}

// ---------------- passA: binned partition + degree count ------------------
// Block-level binning: LDS histogram -> one global atomicAdd per touched
// bucket reserves a contiguous run -> scattered stores land in per-block
// contiguous runs (L2 lines merge instead of 66B-per-store writeback).
__global__ void passA_kernel(const int* __restrict__ src, const int* __restrict__ dst,
                             int* __restrict__ deg, int* __restrict__ cur,
                             unsigned int* __restrict__ entries, int E) {
    __shared__ int hist[NBUCK];
    __shared__ int lbase[NBUCK];
    int t = threadIdx.x;
    for (int i = t; i < NBUCK; i += 256) hist[i] = 0;
    __syncthreads();

    int e0   = blockIdx.x * TILE;
    int eend = min(e0 + TILE, E);

    for (int e = e0 + t; e < eend; e += 256) {
        int d = dst[e];
        atomicAdd(&hist[d >> 8], 1);
        atomicAdd(&deg[d], 1);          // fused degree count
    }
    __syncthreads();
    for (int i = t; i < NBUCK; i += 256) {
        int c = hist[i];
        lbase[i] = (c > 0) ? atomicAdd(&cur[i], c) : 0;
        hist[i] = 0;                    // reuse as local cursor
    }
    __syncthreads();
    for (int e = e0 + t; e < eend; e += 256) {
        int s = src[e];
        int d = dst[e];
        int b = d >> 8;
        int r = atomicAdd(&hist[b], 1);
        int pos = lbase[b] + r;
        if (pos < CAP)                  // safety valve (never triggers: +16 sigma)
            entries[(size_t)b * CAP + pos] = ((unsigned)s << 8) | (unsigned)(d & 255);
    }
}

// ---------------- h' = (x @ W) * dinv[row], stored bf16 -------------------
__global__ void gemm_kernel(const float* __restrict__ x, const float* __restrict__ W,
                            const int* __restrict__ deg, unsigned short* __restrict__ hb,
                            int N) {
    int gid  = blockIdx.x * blockDim.x + threadIdx.x;
    int row  = gid >> 6;
    int lane = gid & 63;
    if (row >= N) return;  // uniform per wave
    float xv  = x[row * DIM + lane];
    float acc = 0.f;
#pragma unroll
    for (int k = 0; k < DIM; ++k) {
        acc = fmaf(__shfl(xv, k, 64), W[k * DIM + lane], acc);
    }
    float di = rsqrtf((float)(deg[row] + 1));  // self-loop included
    hb[row * DIM + lane] = f2bf(acc * di);
}

// ---------------- passB: per-bucket LDS accumulate + epilogue + BN partials
__global__ void __launch_bounds__(512)
passB_kernel(const unsigned int* __restrict__ entries, const int* __restrict__ cur,
             const unsigned short* __restrict__ hb, const int* __restrict__ deg,
             float* __restrict__ out, float* __restrict__ gsum, float* __restrict__ gsumsq,
             int N) {
    __shared__ float accum[BNODES * DIM];  // 64 KB
    int bucket = blockIdx.x;
    int t = threadIdx.x;                   // 512 threads = 8 waves
    int wave = t >> 6, lane = t & 63;
    int node0 = bucket * BNODES;
    int nn = min(BNODES, N - node0);

    float4* a4 = (float4*)accum;
    for (int i = t; i < BNODES * DIM / 4; i += 512) a4[i] = make_float4(0.f, 0.f, 0.f, 0.f);
    __syncthreads();

    int cnt = min(cur[bucket], CAP);
    int per = (cnt + 7) >> 3;              // contiguous chunk per wave
    int beg = wave * per;
    int end = min(beg + per, cnt);
    const unsigned int* eb = entries + (size_t)bucket * CAP;

    for (int base = beg; base < end; base += 64) {
        int idx = base + lane;
        unsigned int ev = (idx < end) ? eb[idx] : 0u;   // coalesced batch
        int cn = min(64, end - base);
        int j = 0;
        for (; j + 4 <= cn; j += 4) {
            unsigned int e0 = __shfl(ev, j,     64);
            unsigned int e1 = __shfl(ev, j + 1, 64);
            unsigned int e2 = __shfl(ev, j + 2, 64);
            unsigned int e3 = __shfl(ev, j + 3, 64);
            float v0 = bf2f(hb[(e0 >> 8) * DIM + lane]);
            float v1 = bf2f(hb[(e1 >> 8) * DIM + lane]);
            float v2 = bf2f(hb[(e2 >> 8) * DIM + lane]);
            float v3 = bf2f(hb[(e3 >> 8) * DIM + lane]);
            atomicAdd(&accum[(e0 & 255) * DIM + lane], v0);
            atomicAdd(&accum[(e1 & 255) * DIM + lane], v1);
            atomicAdd(&accum[(e2 & 255) * DIM + lane], v2);
            atomicAdd(&accum[(e3 & 255) * DIM + lane], v3);
        }
        for (; j < cn; ++j) {
            unsigned int e = __shfl(ev, j, 64);
            float v = bf2f(hb[(e >> 8) * DIM + lane]);
            atomicAdd(&accum[(e & 255) * DIM + lane], v);
        }
    }
    __syncthreads();

    // epilogue: self-loop + dinv scale + coalesced store + BN column partials
    float s_sum = 0.f, s_sq = 0.f;
    for (int i = wave; i < nn; i += 8) {   // wave w owns rows w, w+8, ... (disjoint)
        int node = node0 + i;
        float di = rsqrtf((float)(deg[node] + 1));
        float v = (accum[i * DIM + lane] + bf2f(hb[node * DIM + lane])) * di;
        out[node * DIM + lane] = v;
        s_sum += v;
        s_sq  += v * v;
    }
    __syncthreads();
    accum[wave * 64 + lane]       = s_sum;   // rows 0..15 of accum, safe after barrier
    accum[512 + wave * 64 + lane] = s_sq;
    __syncthreads();
    if (t < 64) {
        float ss = 0.f, qq = 0.f;
#pragma unroll
        for (int w = 0; w < 8; ++w) {
            ss += accum[w * 64 + t];
            qq += accum[512 + w * 64 + t];
        }
        atomicAdd(&gsum[t],   ss);
        atomicAdd(&gsumsq[t], qq);
    }
}

// ---------------- BN finalize: scale/shift per column ---------------------
// bias b cancels in BN (uniform per-column shift), so it's omitted entirely.
__global__ void bn_finalize_kernel(const float* __restrict__ gsum, const float* __restrict__ gsumsq,
                                   const float* __restrict__ gamma, const float* __restrict__ beta,
                                   float* __restrict__ scale, float* __restrict__ shift, int N) {
    int c = threadIdx.x;  // 64 threads
    float invN = 1.0f / (float)N;
    float mean = gsum[c] * invN;
    float var  = gsumsq[c] * invN - mean * mean;
    float sc   = gamma[c] * rsqrtf(var + BN_EPS);
    scale[c] = sc;
    shift[c] = beta[c] - mean * sc;
}

// ---------------- BN apply + ReLU, in place, float4 -----------------------
__global__ void bn_apply_kernel(float4* __restrict__ out, const float* __restrict__ scale,
                                const float* __restrict__ shift, int total4) {
    int i = blockIdx.x * blockDim.x + threadIdx.x;
    if (i >= total4) return;
    int c = (i * 4) & 63;
    float4 v = out[i];
    float a0 = fmaf(v.x, scale[c],     shift[c]);
    float a1 = fmaf(v.y, scale[c + 1], shift[c + 1]);
    float a2 = fmaf(v.z, scale[c + 2], shift[c + 2]);
    float a3 = fmaf(v.w, scale[c + 3], shift[c + 3]);
    v.x = a0 > 0.f ? a0 : 0.f;
    v.y = a1 > 0.f ? a1 : 0.f;
    v.z = a2 > 0.f ? a2 : 0.f;
    v.w = a3 > 0.f ? a3 : 0.f;
    out[i] = v;
}

extern "C" void kernel_launch(void* const* d_in, const int* in_sizes, int n_in,
                              void* d_out, int out_size, void* d_ws, size_t ws_size,
                              hipStream_t stream) {
    const float* x     = (const float*)d_in[0];          // [N, 64]
    const int*   eidx  = (const int*)d_in[1];            // [2, E]
    const float* W     = (const float*)d_in[2];          // [64, 64]
    // d_in[3] = b : cancels in BatchNorm (uniform per-column shift)
    const float* gamma = (const float*)d_in[4];          // [64]
    const float* beta  = (const float*)d_in[5];          // [64]
    float* out = (float*)d_out;                          // [N, 64]

    const int N = N_NODES;
    const int E = N_EDGES;
    const int total = N * DIM;

    const int* src = eidx;
    const int* dst = eidx + E;

    // workspace layout (~21.3 MB)
    unsigned short* hb = (unsigned short*)d_ws;            // N*DIM bf16 (12.8 MB)
    int*   deg       = (int*)(hb + (size_t)N * DIM);       // N        } one
    int*   cur       = deg + N;                            // NBUCK    } contiguous
    float* gsum      = (float*)(cur + NBUCK);              // 64       } memset
    float* gsumsq    = gsum + 64;                          // 64       } region
    float* scale     = gsumsq + 64;                        // 64
    float* shift     = scale + 64;                         // 64
    unsigned int* entries = (unsigned int*)(shift + 64);   // NBUCK*CAP (8 MB)

    // single zero-init of deg + cur + gsum + gsumsq
    hipMemsetAsync(deg, 0, (size_t)(N + NBUCK + 128) * sizeof(int), stream);

    int nblkA = (E + TILE - 1) / TILE;  // 196
    passA_kernel<<<nblkA, 256, 0, stream>>>(src, dst, deg, cur, entries, E);

    gemm_kernel<<<(total + 255) / 256, 256, 0, stream>>>(x, W, deg, hb, N);

    passB_kernel<<<NBUCK, 512, 0, stream>>>(entries, cur, hb, deg, out, gsum, gsumsq, N);

    bn_finalize_kernel<<<1, 64, 0, stream>>>(gsum, gsumsq, gamma, beta, scale, shift, N);
    bn_apply_kernel<<<(total / 4 + 255) / 256, 256, 0, stream>>>((float4*)out, scale, shift, total / 4);
}

// Round 5
// 293.310 us; speedup vs baseline: 3.2847x; 3.2847x over previous
//
#include <hip/hip_runtime.h>

#define N_NODES 100000
#define N_EDGES 1600000
#define DIM 64
#define BN_EPS 1e-5f

#define BNODES 128                        // nodes per bucket (7 bits)
#define NBUCK ((N_NODES + BNODES - 1) / BNODES)  // 782
#define CAP 2560                          // entries/bucket: mean 2046, +11 sigma
#define TILE 8192                         // edges per passA block

// ---- bf16 helpers (manual RNE) -------------------------------------------
static __device__ __forceinline__ unsigned short f2bf(float f) {
    unsigned u = __float_as_uint(f);
    u = (u + 0x7FFFu + ((u >> 16) & 1u)) >> 16;
    return (unsigned short)u;
}
static __device__ __forceinline__ float bf2f(unsigned short h) {
    return __uint_as_float(((unsigned)h) << 16);
}

// ---------------- passA: coarse partition into 128-node buckets -----------
// LDS histogram -> ONE global atomic per (block,bucket) run reservation
// (~153k atomics total, vs 1.6M per-edge atomics in earlier rounds) ->
// packed entries (src<<7 | dst&127) land in contiguous per-block runs.
__global__ void passA_kernel(const int* __restrict__ src, const int* __restrict__ dst,
                             int* __restrict__ cur, unsigned int* __restrict__ entries, int E) {
    __shared__ int hist[NBUCK];
    __shared__ int lbase[NBUCK];
    int t = threadIdx.x;
    for (int i = t; i < NBUCK; i += 256) hist[i] = 0;
    __syncthreads();

    int e0   = blockIdx.x * TILE;
    int eend = min(e0 + TILE, E);

    for (int e = e0 + t; e < eend; e += 256)
        atomicAdd(&hist[dst[e] >> 7], 1);
    __syncthreads();
    for (int i = t; i < NBUCK; i += 256) {
        int c = hist[i];
        lbase[i] = (c > 0) ? atomicAdd(&cur[i], c) : 0;
        hist[i] = 0;                      // reuse as local cursor
    }
    __syncthreads();
    for (int e = e0 + t; e < eend; e += 256) {
        int s = src[e];
        int d = dst[e];
        int b = d >> 7;
        int r = atomicAdd(&hist[b], 1);
        int pos = lbase[b] + r;
        if (pos < CAP)                    // safety valve; statistically never
            entries[(size_t)b * CAP + pos] = ((unsigned)s << 7) | (unsigned)(d & 127);
    }
}

// ---------------- passB1: in-LDS counting sort per bucket -----------------
// Sorts each bucket's entries by node, rewriting entries[] in place as the
// per-node src lists (CSR). The in-bucket histogram IS the exact degree ->
// dinv/rowbeg/rowend written coalesced. No per-edge global atomics anywhere.
__global__ void passB1_kernel(unsigned int* __restrict__ entries, const int* __restrict__ cur,
                              int* __restrict__ rowbeg, int* __restrict__ rowend,
                              float* __restrict__ dinv, int N) {
    __shared__ unsigned int raw[CAP];     // 10 KB
    __shared__ int hist[BNODES];
    __shared__ int sbuf[BNODES];
    __shared__ int startx[BNODES];
    __shared__ int cursor[BNODES];
    int bucket = blockIdx.x;
    int t = threadIdx.x;                  // 256 threads
    int node0 = bucket * BNODES;
    int nn = min(BNODES, N - node0);
    int cnt = min(cur[bucket], CAP);
    unsigned int* eb = entries + (size_t)bucket * CAP;

    if (t < BNODES) hist[t] = 0;
    __syncthreads();
    for (int i = t; i < cnt; i += 256) {
        unsigned int e = eb[i];
        raw[i] = e;
        atomicAdd(&hist[e & 127], 1);
    }
    __syncthreads();
    // inclusive scan of hist (Hillis-Steele, 128 wide, barriers uniform)
    if (t < BNODES) sbuf[t] = hist[t];
    __syncthreads();
    for (int off = 1; off < BNODES; off <<= 1) {
        int add = (t < BNODES && t >= off) ? sbuf[t - off] : 0;
        __syncthreads();
        if (t < BNODES) sbuf[t] += add;
        __syncthreads();
    }
    if (t < BNODES) {
        int ex = sbuf[t] - hist[t];       // exclusive
        startx[t] = ex;
        cursor[t] = ex;
    }
    __syncthreads();
    // scatter src into sorted position (in-place over entries; stores stay
    // inside a 10 KB window -> L2 lines fill and merge)
    for (int i = t; i < cnt; i += 256) {
        unsigned int e = raw[i];
        int d = e & 127;
        int p = atomicAdd(&cursor[d], 1);
        eb[p] = e >> 7;                   // store src only
    }
    // per-node metadata (coalesced)
    if (t < nn) {
        int dg   = hist[t];               // exact degree of this node
        int base = bucket * CAP + startx[t];
        rowbeg[node0 + t] = base;
        rowend[node0 + t] = base + dg;
        dinv[node0 + t]   = rsqrtf((float)(dg + 1));  // self-loop included
    }
}

// ---------------- h' = (x @ W) * dinv[row], stored bf16 -------------------
__global__ void gemm_kernel(const float* __restrict__ x, const float* __restrict__ W,
                            const float* __restrict__ dinv, unsigned short* __restrict__ hb,
                            int N) {
    int gid  = blockIdx.x * blockDim.x + threadIdx.x;
    int row  = gid >> 6;
    int lane = gid & 63;
    if (row >= N) return;  // uniform per wave
    float xv  = x[row * DIM + lane];
    float acc = 0.f;
#pragma unroll
    for (int k = 0; k < DIM; ++k) {
        acc = fmaf(__shfl(xv, k, 64), W[k * DIM + lane], acc);
    }
    hb[row * DIM + lane] = f2bf(acc * dinv[row]);
}

// ---------------- gather: wave/node, lane/feature, batched indices --------
__global__ void gather_kernel(const int* __restrict__ rowbeg, const int* __restrict__ rowend,
                              const unsigned int* __restrict__ srt,
                              const unsigned short* __restrict__ hb,
                              const float* __restrict__ dinv, float* __restrict__ out, int N) {
    int gid  = blockIdx.x * blockDim.x + threadIdx.x;
    int node = gid >> 6;
    int lane = gid & 63;
    if (node >= N) return;  // uniform per wave
    float acc = bf2f(hb[node * DIM + lane]);  // self loop (h' has dinv[node])
    int beg = rowbeg[node];
    int end = rowend[node];
    for (int base = beg; base < end; base += 64) {
        int idx = base + lane;
        unsigned int sv = (idx < end) ? srt[idx] : 0u;  // coalesced index batch
        int cn = min(64, end - base);
        int j = 0;
        for (; j + 4 <= cn; j += 4) {
            unsigned int s0 = __shfl(sv, j,     64);
            unsigned int s1 = __shfl(sv, j + 1, 64);
            unsigned int s2 = __shfl(sv, j + 2, 64);
            unsigned int s3 = __shfl(sv, j + 3, 64);
            float v0 = bf2f(hb[s0 * DIM + lane]);
            float v1 = bf2f(hb[s1 * DIM + lane]);
            float v2 = bf2f(hb[s2 * DIM + lane]);
            float v3 = bf2f(hb[s3 * DIM + lane]);
            acc += (v0 + v1) + (v2 + v3);
        }
        for (; j < cn; ++j) {
            unsigned int s = __shfl(sv, j, 64);
            acc += bf2f(hb[s * DIM + lane]);
        }
    }
    out[node * DIM + lane] = acc * dinv[node];
}

// ---------------- BN reduce: per-column sum / sumsq -----------------------
// bias b cancels in BN (uniform per-column shift), so it's omitted entirely.
__global__ void bn_reduce_kernel(const float* __restrict__ out,
                                 float* __restrict__ gsum, float* __restrict__ gsumsq, int N) {
    __shared__ float ssum[256];
    __shared__ float ssq[256];
    int col = threadIdx.x & 63;
    int sub = threadIdx.x >> 6;  // 0..3
    float s = 0.f, q = 0.f;
    for (int row = blockIdx.x * 4 + sub; row < N; row += gridDim.x * 4) {
        float v = out[row * DIM + col];
        s += v;
        q += v * v;
    }
    ssum[threadIdx.x] = s;
    ssq[threadIdx.x]  = q;
    __syncthreads();
    if (threadIdx.x < 128) {
        ssum[threadIdx.x] += ssum[threadIdx.x + 128];
        ssq[threadIdx.x]  += ssq[threadIdx.x + 128];
    }
    __syncthreads();
    if (threadIdx.x < 64) {
        atomicAdd(&gsum[col],   ssum[threadIdx.x] + ssum[threadIdx.x + 64]);
        atomicAdd(&gsumsq[col], ssq[threadIdx.x]  + ssq[threadIdx.x + 64]);
    }
}

// ---------------- BN finalize: scale/shift per column ---------------------
__global__ void bn_finalize_kernel(const float* __restrict__ gsum, const float* __restrict__ gsumsq,
                                   const float* __restrict__ gamma, const float* __restrict__ beta,
                                   float* __restrict__ scale, float* __restrict__ shift, int N) {
    int c = threadIdx.x;  // 64 threads
    float invN = 1.0f / (float)N;
    float mean = gsum[c] * invN;
    float var  = gsumsq[c] * invN - mean * mean;
    float sc   = gamma[c] * rsqrtf(var + BN_EPS);
    scale[c] = sc;
    shift[c] = beta[c] - mean * sc;
}

// ---------------- BN apply + ReLU, in place, float4 -----------------------
__global__ void bn_apply_kernel(float4* __restrict__ out, const float* __restrict__ scale,
                                const float* __restrict__ shift, int total4) {
    int i = blockIdx.x * blockDim.x + threadIdx.x;
    if (i >= total4) return;
    int c = (i * 4) & 63;
    float4 v = out[i];
    float a0 = fmaf(v.x, scale[c],     shift[c]);
    float a1 = fmaf(v.y, scale[c + 1], shift[c + 1]);
    float a2 = fmaf(v.z, scale[c + 2], shift[c + 2]);
    float a3 = fmaf(v.w, scale[c + 3], shift[c + 3]);
    v.x = a0 > 0.f ? a0 : 0.f;
    v.y = a1 > 0.f ? a1 : 0.f;
    v.z = a2 > 0.f ? a2 : 0.f;
    v.w = a3 > 0.f ? a3 : 0.f;
    out[i] = v;
}

extern "C" void kernel_launch(void* const* d_in, const int* in_sizes, int n_in,
                              void* d_out, int out_size, void* d_ws, size_t ws_size,
                              hipStream_t stream) {
    const float* x     = (const float*)d_in[0];          // [N, 64]
    const int*   eidx  = (const int*)d_in[1];            // [2, E]
    const float* W     = (const float*)d_in[2];          // [64, 64]
    // d_in[3] = b : cancels in BatchNorm (uniform per-column shift)
    const float* gamma = (const float*)d_in[4];          // [64]
    const float* beta  = (const float*)d_in[5];          // [64]
    float* out = (float*)d_out;                          // [N, 64]

    const int N = N_NODES;
    const int E = N_EDGES;
    const int total = N * DIM;

    const int* src = eidx;
    const int* dst = eidx + E;

    // workspace layout (~22.4 MB)
    unsigned short* hb = (unsigned short*)d_ws;            // N*DIM bf16 (12.8 MB)
    float* dinv      = (float*)(hb + (size_t)N * DIM);     // N
    int*   rowbeg    = (int*)(dinv + N);                   // N
    int*   rowend    = rowbeg + N;                         // N
    int*   cur       = rowend + N;                         // NBUCK } one
    float* gsum      = (float*)(cur + NBUCK);              // 64    } memset
    float* gsumsq    = gsum + 64;                          // 64    } region
    float* scale     = gsumsq + 64;                        // 64
    float* shift     = scale + 64;                         // 64
    unsigned int* entries = (unsigned int*)(shift + 64);   // NBUCK*CAP (8.0 MB)

    // zero cur + gsum + gsumsq in one memset
    hipMemsetAsync(cur, 0, (size_t)(NBUCK + 128) * sizeof(int), stream);

    int nblkA = (E + TILE - 1) / TILE;  // 196
    passA_kernel<<<nblkA, 256, 0, stream>>>(src, dst, cur, entries, E);

    passB1_kernel<<<NBUCK, 256, 0, stream>>>(entries, cur, rowbeg, rowend, dinv, N);

    gemm_kernel<<<(total + 255) / 256, 256, 0, stream>>>(x, W, dinv, hb, N);

    gather_kernel<<<(total + 255) / 256, 256, 0, stream>>>(rowbeg, rowend, entries, hb, dinv, out, N);

    bn_reduce_kernel<<<512, 256, 0, stream>>>(out, gsum, gsumsq, N);
    bn_finalize_kernel<<<1, 64, 0, stream>>>(gsum, gsumsq, gamma, beta, scale, shift, N);
    bn_apply_kernel<<<(total / 4 + 255) / 256, 256, 0, stream>>>((float4*)out, scale, shift, total / 4);
}

// Round 6
// 258.657 us; speedup vs baseline: 3.7248x; 1.1340x over previous
//
#include <hip/hip_runtime.h>

#define N_NODES 100000
#define N_EDGES 1600000
#define DIM 64
#define BN_EPS 1e-5f

#define BNODES 128                        // nodes per bucket (7 bits)
#define NBUCK ((N_NODES + BNODES - 1) / BNODES)  // 782
#define CAP 2560                          // entries/bucket: mean 2046, +11 sigma
#define TILE 8192                         // edges per passA block

typedef __bf16 bf16x8 __attribute__((ext_vector_type(8)));
typedef float floatx4 __attribute__((ext_vector_type(4)));

// ---- bf16 helpers (manual RNE) -------------------------------------------
static __device__ __forceinline__ unsigned short f2bf(float f) {
    unsigned u = __float_as_uint(f);
    u = (u + 0x7FFFu + ((u >> 16) & 1u)) >> 16;
    return (unsigned short)u;
}
static __device__ __forceinline__ float bf2f(unsigned short h) {
    return __uint_as_float(((unsigned)h) << 16);
}

// ---------------- passA: coarse partition into 128-node buckets -----------
__global__ void passA_kernel(const int* __restrict__ src, const int* __restrict__ dst,
                             int* __restrict__ cur, unsigned int* __restrict__ entries, int E) {
    __shared__ int hist[NBUCK];
    __shared__ int lbase[NBUCK];
    int t = threadIdx.x;
    for (int i = t; i < NBUCK; i += 256) hist[i] = 0;
    __syncthreads();

    int e0   = blockIdx.x * TILE;
    int eend = min(e0 + TILE, E);

    for (int e = e0 + t; e < eend; e += 256)
        atomicAdd(&hist[dst[e] >> 7], 1);
    __syncthreads();
    for (int i = t; i < NBUCK; i += 256) {
        int c = hist[i];
        lbase[i] = (c > 0) ? atomicAdd(&cur[i], c) : 0;
        hist[i] = 0;                      // reuse as local cursor
    }
    __syncthreads();
    for (int e = e0 + t; e < eend; e += 256) {
        int s = src[e];
        int d = dst[e];
        int b = d >> 7;
        int r = atomicAdd(&hist[b], 1);
        int pos = lbase[b] + r;
        if (pos < CAP)                    // safety valve; statistically never
            entries[(size_t)b * CAP + pos] = ((unsigned)s << 7) | (unsigned)(d & 127);
    }
}

// ---------------- passB1: in-LDS counting sort per bucket -----------------
__global__ void passB1_kernel(unsigned int* __restrict__ entries, const int* __restrict__ cur,
                              int* __restrict__ rowbeg, int* __restrict__ rowend,
                              float* __restrict__ dinv, int N) {
    __shared__ unsigned int raw[CAP];     // 10 KB
    __shared__ int hist[BNODES];
    __shared__ int sbuf[BNODES];
    __shared__ int startx[BNODES];
    __shared__ int cursor[BNODES];
    int bucket = blockIdx.x;
    int t = threadIdx.x;                  // 256 threads
    int node0 = bucket * BNODES;
    int nn = min(BNODES, N - node0);
    int cnt = min(cur[bucket], CAP);
    unsigned int* eb = entries + (size_t)bucket * CAP;

    if (t < BNODES) hist[t] = 0;
    __syncthreads();
    for (int i = t; i < cnt; i += 256) {
        unsigned int e = eb[i];
        raw[i] = e;
        atomicAdd(&hist[e & 127], 1);
    }
    __syncthreads();
    if (t < BNODES) sbuf[t] = hist[t];
    __syncthreads();
    for (int off = 1; off < BNODES; off <<= 1) {
        int add = (t < BNODES && t >= off) ? sbuf[t - off] : 0;
        __syncthreads();
        if (t < BNODES) sbuf[t] += add;
        __syncthreads();
    }
    if (t < BNODES) {
        int ex = sbuf[t] - hist[t];       // exclusive
        startx[t] = ex;
        cursor[t] = ex;
    }
    __syncthreads();
    for (int i = t; i < cnt; i += 256) {
        unsigned int e = raw[i];
        int d = e & 127;
        int p = atomicAdd(&cursor[d], 1);
        eb[p] = e >> 7;                   // store src only
    }
    if (t < nn) {
        int dg   = hist[t];               // exact degree of this node
        int base = bucket * CAP + startx[t];
        rowbeg[node0 + t] = base;
        rowend[node0 + t] = base + dg;
        dinv[node0 + t]   = rsqrtf((float)(dg + 1));  // self-loop included
    }
}

// ---------------- h' = (x @ W) * dinv[row] via bf16 MFMA ------------------
// Per wave: 16 rows x 64 cols. W (16 KB) held as 8 register B-fragments,
// loaded once per wave and reused across row-chunks. Layouts per cdna4 docs:
//   A[m=lane&15][k=quad*8+j], B[k=quad*8+j][n=lane&15],
//   D: col=lane&15, row=quad*4+reg.
__global__ void __launch_bounds__(256)
gemm_kernel(const float* __restrict__ x, const float* __restrict__ W,
            const float* __restrict__ dinv, unsigned short* __restrict__ hb, int N) {
    int wave  = (blockIdx.x * blockDim.x + threadIdx.x) >> 6;
    int lane  = threadIdx.x & 63;
    int m     = lane & 15;
    int quad  = lane >> 4;

    bf16x8 bfrag[2][4];                   // [kchunk][ntile]
#pragma unroll
    for (int c = 0; c < 2; ++c)
#pragma unroll
        for (int nt = 0; nt < 4; ++nt) {
            bf16x8 f;
#pragma unroll
            for (int j = 0; j < 8; ++j) {
                int k = c * 32 + quad * 8 + j;
                f[j] = (__bf16)W[k * DIM + nt * 16 + m];
            }
            bfrag[c][nt] = f;
        }

    int nchunks    = N >> 4;              // 6250 (N divisible by 16)
    int totalwaves = (gridDim.x * blockDim.x) >> 6;
    for (int chunk = wave; chunk < nchunks; chunk += totalwaves) {
        int row0 = chunk * 16;
        const float* xr = x + (size_t)(row0 + m) * DIM;
        bf16x8 afrag[2];
#pragma unroll
        for (int c = 0; c < 2; ++c) {
            float4 lo = *(const float4*)(xr + c * 32 + quad * 8);
            float4 hi = *(const float4*)(xr + c * 32 + quad * 8 + 4);
            bf16x8 f;
            f[0] = (__bf16)lo.x; f[1] = (__bf16)lo.y; f[2] = (__bf16)lo.z; f[3] = (__bf16)lo.w;
            f[4] = (__bf16)hi.x; f[5] = (__bf16)hi.y; f[6] = (__bf16)hi.z; f[7] = (__bf16)hi.w;
            afrag[c] = f;
        }
        float dv[4];
#pragma unroll
        for (int r = 0; r < 4; ++r) dv[r] = dinv[row0 + quad * 4 + r];
#pragma unroll
        for (int nt = 0; nt < 4; ++nt) {
            floatx4 acc = {0.f, 0.f, 0.f, 0.f};
            acc = __builtin_amdgcn_mfma_f32_16x16x32_bf16(afrag[0], bfrag[0][nt], acc, 0, 0, 0);
            acc = __builtin_amdgcn_mfma_f32_16x16x32_bf16(afrag[1], bfrag[1][nt], acc, 0, 0, 0);
#pragma unroll
            for (int r = 0; r < 4; ++r) {
                int row = row0 + quad * 4 + r;
                hb[(size_t)row * DIM + nt * 16 + m] = f2bf(acc[r] * dv[r]);
            }
        }
    }
}

// ---------------- gather + fused BN column partials -----------------------
__global__ void __launch_bounds__(256)
gather_kernel(const int* __restrict__ rowbeg, const int* __restrict__ rowend,
              const unsigned int* __restrict__ srt, const unsigned short* __restrict__ hb,
              const float* __restrict__ dinv, float* __restrict__ out,
              float* __restrict__ gsum, float* __restrict__ gsumsq, int N) {
    __shared__ float red[2][4][64];
    int lane = threadIdx.x & 63;
    int wv   = threadIdx.x >> 6;          // 0..3
    int gwave  = blockIdx.x * 4 + wv;
    int nwaves = gridDim.x * 4;
    float s_sum = 0.f, s_sq = 0.f;

    for (int node = gwave; node < N; node += nwaves) {
        float acc = bf2f(hb[node * DIM + lane]);  // self loop (h' has dinv[node])
        int beg = rowbeg[node];
        int end = rowend[node];
        for (int base = beg; base < end; base += 64) {
            int idx = base + lane;
            unsigned int sv = (idx < end) ? srt[idx] : 0u;  // coalesced index batch
            int cn = min(64, end - base);
            int j = 0;
            for (; j + 4 <= cn; j += 4) {
                unsigned int s0 = __shfl(sv, j,     64);
                unsigned int s1 = __shfl(sv, j + 1, 64);
                unsigned int s2 = __shfl(sv, j + 2, 64);
                unsigned int s3 = __shfl(sv, j + 3, 64);
                float v0 = bf2f(hb[s0 * DIM + lane]);
                float v1 = bf2f(hb[s1 * DIM + lane]);
                float v2 = bf2f(hb[s2 * DIM + lane]);
                float v3 = bf2f(hb[s3 * DIM + lane]);
                acc += (v0 + v1) + (v2 + v3);
            }
            for (; j < cn; ++j) {
                unsigned int s = __shfl(sv, j, 64);
                acc += bf2f(hb[s * DIM + lane]);
            }
        }
        float v = acc * dinv[node];
        out[node * DIM + lane] = v;
        s_sum += v;
        s_sq  += v * v;
    }

    red[0][wv][lane] = s_sum;
    red[1][wv][lane] = s_sq;
    __syncthreads();
    if (threadIdx.x < 64) {
        int c = threadIdx.x;
        atomicAdd(&gsum[c],   red[0][0][c] + red[0][1][c] + red[0][2][c] + red[0][3][c]);
        atomicAdd(&gsumsq[c], red[1][0][c] + red[1][1][c] + red[1][2][c] + red[1][3][c]);
    }
}

// ---------------- BN finalize: scale/shift per column ---------------------
// bias b cancels in BN (uniform per-column shift), so it's omitted entirely.
__global__ void bn_finalize_kernel(const float* __restrict__ gsum, const float* __restrict__ gsumsq,
                                   const float* __restrict__ gamma, const float* __restrict__ beta,
                                   float* __restrict__ scale, float* __restrict__ shift, int N) {
    int c = threadIdx.x;  // 64 threads
    float invN = 1.0f / (float)N;
    float mean = gsum[c] * invN;
    float var  = gsumsq[c] * invN - mean * mean;
    float sc   = gamma[c] * rsqrtf(var + BN_EPS);
    scale[c] = sc;
    shift[c] = beta[c] - mean * sc;
}

// ---------------- BN apply + ReLU, in place, float4 -----------------------
__global__ void bn_apply_kernel(float4* __restrict__ out, const float* __restrict__ scale,
                                const float* __restrict__ shift, int total4) {
    int i = blockIdx.x * blockDim.x + threadIdx.x;
    if (i >= total4) return;
    int c = (i * 4) & 63;
    float4 v = out[i];
    float a0 = fmaf(v.x, scale[c],     shift[c]);
    float a1 = fmaf(v.y, scale[c + 1], shift[c + 1]);
    float a2 = fmaf(v.z, scale[c + 2], shift[c + 2]);
    float a3 = fmaf(v.w, scale[c + 3], shift[c + 3]);
    v.x = a0 > 0.f ? a0 : 0.f;
    v.y = a1 > 0.f ? a1 : 0.f;
    v.z = a2 > 0.f ? a2 : 0.f;
    v.w = a3 > 0.f ? a3 : 0.f;
    out[i] = v;
}

extern "C" void kernel_launch(void* const* d_in, const int* in_sizes, int n_in,
                              void* d_out, int out_size, void* d_ws, size_t ws_size,
                              hipStream_t stream) {
    const float* x     = (const float*)d_in[0];          // [N, 64]
    const int*   eidx  = (const int*)d_in[1];            // [2, E]
    const float* W     = (const float*)d_in[2];          // [64, 64]
    // d_in[3] = b : cancels in BatchNorm (uniform per-column shift)
    const float* gamma = (const float*)d_in[4];          // [64]
    const float* beta  = (const float*)d_in[5];          // [64]
    float* out = (float*)d_out;                          // [N, 64]

    const int N = N_NODES;
    const int E = N_EDGES;
    const int total = N * DIM;

    const int* src = eidx;
    const int* dst = eidx + E;

    // workspace layout (~22.4 MB)
    unsigned short* hb = (unsigned short*)d_ws;            // N*DIM bf16 (12.8 MB)
    float* dinv      = (float*)(hb + (size_t)N * DIM);     // N
    int*   rowbeg    = (int*)(dinv + N);                   // N
    int*   rowend    = rowbeg + N;                         // N
    int*   cur       = rowend + N;                         // NBUCK } one
    float* gsum      = (float*)(cur + NBUCK);              // 64    } memset
    float* gsumsq    = gsum + 64;                          // 64    } region
    float* scale     = gsumsq + 64;                        // 64
    float* shift     = scale + 64;                         // 64
    unsigned int* entries = (unsigned int*)(shift + 64);   // NBUCK*CAP (8.0 MB)

    // zero cur + gsum + gsumsq in one memset
    hipMemsetAsync(cur, 0, (size_t)(NBUCK + 128) * sizeof(int), stream);

    int nblkA = (E + TILE - 1) / TILE;  // 196
    passA_kernel<<<nblkA, 256, 0, stream>>>(src, dst, cur, entries, E);

    passB1_kernel<<<NBUCK, 256, 0, stream>>>(entries, cur, rowbeg, rowend, dinv, N);

    gemm_kernel<<<512, 256, 0, stream>>>(x, W, dinv, hb, N);

    gather_kernel<<<2048, 256, 0, stream>>>(rowbeg, rowend, entries, hb, dinv, out,
                                            gsum, gsumsq, N);

    bn_finalize_kernel<<<1, 64, 0, stream>>>(gsum, gsumsq, gamma, beta, scale, shift, N);
    bn_apply_kernel<<<(total / 4 + 255) / 256, 256, 0, stream>>>((float4*)out, scale, shift, total / 4);
}

// Round 7
// 232.323 us; speedup vs baseline: 4.1470x; 1.1134x over previous
//
#include <hip/hip_runtime.h>

#define N_NODES 100000
#define N_EDGES 1600000
#define DIM 64
#define BN_EPS 1e-5f

#define BNODES 128                        // nodes per bucket (7 bits)
#define NBUCK ((N_NODES + BNODES - 1) / BNODES)  // 782
#define CAP 2560                          // entries/bucket: mean 2046, +11 sigma
#define TILE 8192                         // edges per passA block

typedef __bf16 bf16x8 __attribute__((ext_vector_type(8)));
typedef float floatx4 __attribute__((ext_vector_type(4)));

// ---- bf16 helpers (manual RNE) -------------------------------------------
static __device__ __forceinline__ unsigned short f2bf(float f) {
    unsigned u = __float_as_uint(f);
    u = (u + 0x7FFFu + ((u >> 16) & 1u)) >> 16;
    return (unsigned short)u;
}
static __device__ __forceinline__ float bf2f(unsigned short h) {
    return __uint_as_float(((unsigned)h) << 16);
}

// ---------------- passA: coarse partition into 128-node buckets -----------
__global__ void passA_kernel(const int* __restrict__ src, const int* __restrict__ dst,
                             int* __restrict__ cur, unsigned int* __restrict__ entries, int E) {
    __shared__ int hist[NBUCK];
    __shared__ int lbase[NBUCK];
    int t = threadIdx.x;
    for (int i = t; i < NBUCK; i += 256) hist[i] = 0;
    __syncthreads();

    int e0   = blockIdx.x * TILE;
    int eend = min(e0 + TILE, E);

    for (int e = e0 + t; e < eend; e += 256)
        atomicAdd(&hist[dst[e] >> 7], 1);
    __syncthreads();
    for (int i = t; i < NBUCK; i += 256) {
        int c = hist[i];
        lbase[i] = (c > 0) ? atomicAdd(&cur[i], c) : 0;
        hist[i] = 0;                      // reuse as local cursor
    }
    __syncthreads();
    for (int e = e0 + t; e < eend; e += 256) {
        int s = src[e];
        int d = dst[e];
        int b = d >> 7;
        int r = atomicAdd(&hist[b], 1);
        int pos = lbase[b] + r;
        if (pos < CAP)                    // safety valve; statistically never
            entries[(size_t)b * CAP + pos] = ((unsigned)s << 7) | (unsigned)(d & 127);
    }
}

// ---------------- passB1: in-LDS counting sort per bucket -----------------
__global__ void passB1_kernel(unsigned int* __restrict__ entries, const int* __restrict__ cur,
                              int* __restrict__ rowbeg, int* __restrict__ rowend,
                              float* __restrict__ dinv, int N) {
    __shared__ unsigned int raw[CAP];     // 10 KB
    __shared__ int hist[BNODES];
    __shared__ int sbuf[BNODES];
    __shared__ int startx[BNODES];
    __shared__ int cursor[BNODES];
    int bucket = blockIdx.x;
    int t = threadIdx.x;                  // 256 threads
    int node0 = bucket * BNODES;
    int nn = min(BNODES, N - node0);
    int cnt = min(cur[bucket], CAP);
    unsigned int* eb = entries + (size_t)bucket * CAP;

    if (t < BNODES) hist[t] = 0;
    __syncthreads();
    for (int i = t; i < cnt; i += 256) {
        unsigned int e = eb[i];
        raw[i] = e;
        atomicAdd(&hist[e & 127], 1);
    }
    __syncthreads();
    if (t < BNODES) sbuf[t] = hist[t];
    __syncthreads();
    for (int off = 1; off < BNODES; off <<= 1) {
        int add = (t < BNODES && t >= off) ? sbuf[t - off] : 0;
        __syncthreads();
        if (t < BNODES) sbuf[t] += add;
        __syncthreads();
    }
    if (t < BNODES) {
        int ex = sbuf[t] - hist[t];       // exclusive
        startx[t] = ex;
        cursor[t] = ex;
    }
    __syncthreads();
    for (int i = t; i < cnt; i += 256) {
        unsigned int e = raw[i];
        int d = e & 127;
        int p = atomicAdd(&cursor[d], 1);
        eb[p] = e >> 7;                   // store src only
    }
    if (t < nn) {
        int dg   = hist[t];               // exact degree of this node
        int base = bucket * CAP + startx[t];
        rowbeg[node0 + t] = base;
        rowend[node0 + t] = base + dg;
        dinv[node0 + t]   = rsqrtf((float)(dg + 1));  // self-loop included
    }
}

// ---------------- h' = (x @ W) * dinv[row] via bf16 MFMA ------------------
__global__ void __launch_bounds__(256)
gemm_kernel(const float* __restrict__ x, const float* __restrict__ W,
            const float* __restrict__ dinv, unsigned short* __restrict__ hb, int N) {
    int wave  = (blockIdx.x * blockDim.x + threadIdx.x) >> 6;
    int lane  = threadIdx.x & 63;
    int m     = lane & 15;
    int quad  = lane >> 4;

    bf16x8 bfrag[2][4];                   // [kchunk][ntile]
#pragma unroll
    for (int c = 0; c < 2; ++c)
#pragma unroll
        for (int nt = 0; nt < 4; ++nt) {
            bf16x8 f;
#pragma unroll
            for (int j = 0; j < 8; ++j) {
                int k = c * 32 + quad * 8 + j;
                f[j] = (__bf16)W[k * DIM + nt * 16 + m];
            }
            bfrag[c][nt] = f;
        }

    int nchunks    = N >> 4;              // 6250
    int totalwaves = (gridDim.x * blockDim.x) >> 6;
    for (int chunk = wave; chunk < nchunks; chunk += totalwaves) {
        int row0 = chunk * 16;
        const float* xr = x + (size_t)(row0 + m) * DIM;
        bf16x8 afrag[2];
#pragma unroll
        for (int c = 0; c < 2; ++c) {
            float4 lo = *(const float4*)(xr + c * 32 + quad * 8);
            float4 hi = *(const float4*)(xr + c * 32 + quad * 8 + 4);
            bf16x8 f;
            f[0] = (__bf16)lo.x; f[1] = (__bf16)lo.y; f[2] = (__bf16)lo.z; f[3] = (__bf16)lo.w;
            f[4] = (__bf16)hi.x; f[5] = (__bf16)hi.y; f[6] = (__bf16)hi.z; f[7] = (__bf16)hi.w;
            afrag[c] = f;
        }
        float dv[4];
#pragma unroll
        for (int r = 0; r < 4; ++r) dv[r] = dinv[row0 + quad * 4 + r];
#pragma unroll
        for (int nt = 0; nt < 4; ++nt) {
            floatx4 acc = {0.f, 0.f, 0.f, 0.f};
            acc = __builtin_amdgcn_mfma_f32_16x16x32_bf16(afrag[0], bfrag[0][nt], acc, 0, 0, 0);
            acc = __builtin_amdgcn_mfma_f32_16x16x32_bf16(afrag[1], bfrag[1][nt], acc, 0, 0, 0);
#pragma unroll
            for (int r = 0; r < 4; ++r) {
                int row = row0 + quad * 4 + r;
                hb[(size_t)row * DIM + nt * 16 + m] = f2bf(acc[r] * dv[r]);
            }
        }
    }
}

// ---------------- gather: 4 nodes/wave, merged contiguous edge stream -----
// passB1's CSR is contiguous within a bucket and 4-node groups never straddle
// a 128-node bucket, so [rowbeg[4i], rowend[4i+3]) is one run with 3 uniform
// split points. One 64-wide index batch covers ~64 edges (4x less masked
// waste) and the 8-wide unroll keeps 8 independent hb-row loads in flight.
__global__ void __launch_bounds__(256)
gather_kernel(const int* __restrict__ rowbeg, const int* __restrict__ rowend,
              const unsigned int* __restrict__ srt, const unsigned short* __restrict__ hb,
              const float* __restrict__ dinv, float* __restrict__ out, int N) {
    int gid  = blockIdx.x * blockDim.x + threadIdx.x;
    int g    = gid >> 6;
    int lane = gid & 63;
    int n0   = g << 2;
    if (n0 >= N) return;  // uniform per wave; N % 4 == 0
    int beg = rowbeg[n0];
    int s1  = rowbeg[n0 + 1];
    int s2  = rowbeg[n0 + 2];
    int s3  = rowbeg[n0 + 3];
    int end = rowend[n0 + 3];
    float acc0 = bf2f(hb[(size_t)(n0 + 0) * DIM + lane]);  // self loops
    float acc1 = bf2f(hb[(size_t)(n0 + 1) * DIM + lane]);
    float acc2 = bf2f(hb[(size_t)(n0 + 2) * DIM + lane]);
    float acc3 = bf2f(hb[(size_t)(n0 + 3) * DIM + lane]);

    for (int base = beg; base < end; base += 64) {
        int idx = base + lane;
        unsigned int sv = (idx < end) ? srt[idx] : 0u;  // coalesced index batch
        int cn = min(64, end - base);
        int j = 0;
        for (; j + 8 <= cn; j += 8) {
            float v[8];
#pragma unroll
            for (int u = 0; u < 8; ++u) {
                unsigned int s = __shfl(sv, j + u, 64);
                v[u] = bf2f(hb[(size_t)s * DIM + lane]);
            }
#pragma unroll
            for (int u = 0; u < 8; ++u) {
                int p = base + j + u;
                acc0 += (p < s1) ? v[u] : 0.f;
                acc1 += (p >= s1 && p < s2) ? v[u] : 0.f;
                acc2 += (p >= s2 && p < s3) ? v[u] : 0.f;
                acc3 += (p >= s3) ? v[u] : 0.f;
            }
        }
        for (; j < cn; ++j) {
            unsigned int s = __shfl(sv, j, 64);
            float vv = bf2f(hb[(size_t)s * DIM + lane]);
            int p = base + j;
            if (p < s1)      acc0 += vv;
            else if (p < s2) acc1 += vv;
            else if (p < s3) acc2 += vv;
            else             acc3 += vv;
        }
    }
    out[(size_t)(n0 + 0) * DIM + lane] = acc0 * dinv[n0 + 0];
    out[(size_t)(n0 + 1) * DIM + lane] = acc1 * dinv[n0 + 1];
    out[(size_t)(n0 + 2) * DIM + lane] = acc2 * dinv[n0 + 2];
    out[(size_t)(n0 + 3) * DIM + lane] = acc3 * dinv[n0 + 3];
}

// ---------------- BN reduce: per-column sum / sumsq -----------------------
// bias b cancels in BN (uniform per-column shift), so it's omitted entirely.
__global__ void bn_reduce_kernel(const float* __restrict__ out,
                                 float* __restrict__ gsum, float* __restrict__ gsumsq, int N) {
    __shared__ float ssum[256];
    __shared__ float ssq[256];
    int col = threadIdx.x & 63;
    int sub = threadIdx.x >> 6;  // 0..3
    float s = 0.f, q = 0.f;
    for (int row = blockIdx.x * 4 + sub; row < N; row += gridDim.x * 4) {
        float v = out[row * DIM + col];
        s += v;
        q += v * v;
    }
    ssum[threadIdx.x] = s;
    ssq[threadIdx.x]  = q;
    __syncthreads();
    if (threadIdx.x < 128) {
        ssum[threadIdx.x] += ssum[threadIdx.x + 128];
        ssq[threadIdx.x]  += ssq[threadIdx.x + 128];
    }
    __syncthreads();
    if (threadIdx.x < 64) {
        atomicAdd(&gsum[col],   ssum[threadIdx.x] + ssum[threadIdx.x + 64]);
        atomicAdd(&gsumsq[col], ssq[threadIdx.x]  + ssq[threadIdx.x + 64]);
    }
}

// ---------------- BN finalize: scale/shift per column ---------------------
__global__ void bn_finalize_kernel(const float* __restrict__ gsum, const float* __restrict__ gsumsq,
                                   const float* __restrict__ gamma, const float* __restrict__ beta,
                                   float* __restrict__ scale, float* __restrict__ shift, int N) {
    int c = threadIdx.x;  // 64 threads
    float invN = 1.0f / (float)N;
    float mean = gsum[c] * invN;
    float var  = gsumsq[c] * invN - mean * mean;
    float sc   = gamma[c] * rsqrtf(var + BN_EPS);
    scale[c] = sc;
    shift[c] = beta[c] - mean * sc;
}

// ---------------- BN apply + ReLU, in place, float4 -----------------------
__global__ void bn_apply_kernel(float4* __restrict__ out, const float* __restrict__ scale,
                                const float* __restrict__ shift, int total4) {
    int i = blockIdx.x * blockDim.x + threadIdx.x;
    if (i >= total4) return;
    int c = (i * 4) & 63;
    float4 v = out[i];
    float a0 = fmaf(v.x, scale[c],     shift[c]);
    float a1 = fmaf(v.y, scale[c + 1], shift[c + 1]);
    float a2 = fmaf(v.z, scale[c + 2], shift[c + 2]);
    float a3 = fmaf(v.w, scale[c + 3], shift[c + 3]);
    v.x = a0 > 0.f ? a0 : 0.f;
    v.y = a1 > 0.f ? a1 : 0.f;
    v.z = a2 > 0.f ? a2 : 0.f;
    v.w = a3 > 0.f ? a3 : 0.f;
    out[i] = v;
}

extern "C" void kernel_launch(void* const* d_in, const int* in_sizes, int n_in,
                              void* d_out, int out_size, void* d_ws, size_t ws_size,
                              hipStream_t stream) {
    const float* x     = (const float*)d_in[0];          // [N, 64]
    const int*   eidx  = (const int*)d_in[1];            // [2, E]
    const float* W     = (const float*)d_in[2];          // [64, 64]
    // d_in[3] = b : cancels in BatchNorm (uniform per-column shift)
    const float* gamma = (const float*)d_in[4];          // [64]
    const float* beta  = (const float*)d_in[5];          // [64]
    float* out = (float*)d_out;                          // [N, 64]

    const int N = N_NODES;
    const int E = N_EDGES;
    const int total = N * DIM;

    const int* src = eidx;
    const int* dst = eidx + E;

    // workspace layout (~22.4 MB)
    unsigned short* hb = (unsigned short*)d_ws;            // N*DIM bf16 (12.8 MB)
    float* dinv      = (float*)(hb + (size_t)N * DIM);     // N
    int*   rowbeg    = (int*)(dinv + N);                   // N
    int*   rowend    = rowbeg + N;                         // N
    int*   cur       = rowend + N;                         // NBUCK } one
    float* gsum      = (float*)(cur + NBUCK);              // 64    } memset
    float* gsumsq    = gsum + 64;                          // 64    } region
    float* scale     = gsumsq + 64;                        // 64
    float* shift     = scale + 64;                         // 64
    unsigned int* entries = (unsigned int*)(shift + 64);   // NBUCK*CAP (8.0 MB)

    // zero cur + gsum + gsumsq in one memset
    hipMemsetAsync(cur, 0, (size_t)(NBUCK + 128) * sizeof(int), stream);

    int nblkA = (E + TILE - 1) / TILE;  // 196
    passA_kernel<<<nblkA, 256, 0, stream>>>(src, dst, cur, entries, E);

    passB1_kernel<<<NBUCK, 256, 0, stream>>>(entries, cur, rowbeg, rowend, dinv, N);

    gemm_kernel<<<512, 256, 0, stream>>>(x, W, dinv, hb, N);

    // 25000 waves (4 nodes each) = 6250 blocks
    gather_kernel<<<(N / 4 + 3) / 4, 256, 0, stream>>>(rowbeg, rowend, entries, hb, dinv, out, N);

    bn_reduce_kernel<<<512, 256, 0, stream>>>(out, gsum, gsumsq, N);
    bn_finalize_kernel<<<1, 64, 0, stream>>>(gsum, gsumsq, gamma, beta, scale, shift, N);
    bn_apply_kernel<<<(total / 4 + 255) / 256, 256, 0, stream>>>((float4*)out, scale, shift, total / 4);
}